// Round 3
// baseline (3691.664 us; speedup 1.0000x reference)
//
#include <hip/hip_runtime.h>

// ---------------------------------------------------------------------------
// FluxIPAttnProcessor — round 3: ALL-FP32 I/O (reference dtype is float32).
// H=24, DH=128, TXT=512, IMG=1024, S=1536, HID=3072, IPD=1152, IPL=128
// Round-2 NaN root cause: inputs/outputs were read/written as bf16, but the
// reference (and harness buffers) are float32. Reading fp32 as bf16 yields
// +-1e38 garbage -> inf-inf -> NaN in softmax.
// Workspace: 19,660,800 floats = 78.6 MB (KIP/VIP and IPO alias AOUT).
// ---------------------------------------------------------------------------

#define HID 3072
#define DH 128
#define NH 24
#define TXT 512
#define SIMG 1024
#define SFULL 1536
#define IPL 128
#define IPD 1152
#define ATTN_SCALE 0.08838834764831845f  // 1/sqrt(128)

// ---- block-of-128 reductions (tree in LDS) --------------------------------
__device__ __forceinline__ float blk_sum128(float v, float* red) {
  int d = threadIdx.x;
  red[d] = v; __syncthreads();
  if (d < 64) red[d] += red[d + 64]; __syncthreads();
  if (d < 32) red[d] += red[d + 32]; __syncthreads();
  if (d < 16) red[d] += red[d + 16]; __syncthreads();
  if (d < 8)  red[d] += red[d + 8];  __syncthreads();
  if (d < 4)  red[d] += red[d + 4];  __syncthreads();
  if (d < 2)  red[d] += red[d + 2];  __syncthreads();
  if (d < 1)  red[d] += red[d + 1];  __syncthreads();
  float r = red[0]; __syncthreads();
  return r;
}
__device__ __forceinline__ float blk_max128(float v, float* red) {
  int d = threadIdx.x;
  red[d] = v; __syncthreads();
  if (d < 64) red[d] = fmaxf(red[d], red[d + 64]); __syncthreads();
  if (d < 32) red[d] = fmaxf(red[d], red[d + 32]); __syncthreads();
  if (d < 16) red[d] = fmaxf(red[d], red[d + 16]); __syncthreads();
  if (d < 8)  red[d] = fmaxf(red[d], red[d + 8]);  __syncthreads();
  if (d < 4)  red[d] = fmaxf(red[d], red[d + 4]);  __syncthreads();
  if (d < 2)  red[d] = fmaxf(red[d], red[d + 2]);  __syncthreads();
  if (d < 1)  red[d] = fmaxf(red[d], red[d + 1]);  __syncthreads();
  float r = red[0]; __syncthreads();
  return r;
}

// ---------------------------------------------------------------------------
// GEMM: C[M,N] = A[M,K] @ W[N,K]^T + bias[N].  64x64 tile, BK=16, 4x4/thread.
// M % 64 == 0, N % 64 == 0, K % 16 == 0 (holds for all our shapes).
// ---------------------------------------------------------------------------
__global__ __launch_bounds__(256) void gemm_bias(
    const float* __restrict__ A, const float* __restrict__ W,
    const float* __restrict__ bias, float* __restrict__ C,
    int M, int N, int K) {
  __shared__ float As[16][68];
  __shared__ float Bs[16][68];
  const int tid = threadIdx.x;
  const int tx = tid & 15, ty = tid >> 4;
  const int m0 = blockIdx.y * 64, n0 = blockIdx.x * 64;
  const int lr = tid >> 2;          // 0..63 row within tile for staging
  const int lk = (tid & 3) * 4;     // 0,4,8,12 k-offset for staging
  float acc[4][4] = {};
  for (int k0 = 0; k0 < K; k0 += 16) {
    float4 av = *(const float4*)(A + (size_t)(m0 + lr) * K + k0 + lk);
    float4 wv = *(const float4*)(W + (size_t)(n0 + lr) * K + k0 + lk);
    As[lk + 0][lr] = av.x; As[lk + 1][lr] = av.y; As[lk + 2][lr] = av.z; As[lk + 3][lr] = av.w;
    Bs[lk + 0][lr] = wv.x; Bs[lk + 1][lr] = wv.y; Bs[lk + 2][lr] = wv.z; Bs[lk + 3][lr] = wv.w;
    __syncthreads();
#pragma unroll
    for (int kk = 0; kk < 16; ++kk) {
      float4 a = *(const float4*)&As[kk][ty * 4];
      float4 b = *(const float4*)&Bs[kk][tx * 4];
      acc[0][0] += a.x * b.x; acc[0][1] += a.x * b.y; acc[0][2] += a.x * b.z; acc[0][3] += a.x * b.w;
      acc[1][0] += a.y * b.x; acc[1][1] += a.y * b.y; acc[1][2] += a.y * b.z; acc[1][3] += a.y * b.w;
      acc[2][0] += a.z * b.x; acc[2][1] += a.z * b.y; acc[2][2] += a.z * b.z; acc[2][3] += a.z * b.w;
      acc[3][0] += a.w * b.x; acc[3][1] += a.w * b.y; acc[3][2] += a.w * b.z; acc[3][3] += a.w * b.w;
    }
    __syncthreads();
  }
  float bb[4];
#pragma unroll
  for (int j = 0; j < 4; ++j) bb[j] = bias[n0 + tx * 4 + j];
#pragma unroll
  for (int i = 0; i < 4; ++i) {
    size_t row = (size_t)(m0 + ty * 4 + i);
#pragma unroll
    for (int j = 0; j < 4; ++j)
      C[row * N + (n0 + tx * 4 + j)] = acc[i][j] + bb[j];
  }
}

// ---------------------------------------------------------------------------
// Reorder (L,3072)->(H,L,128) with optional per-head RMS norm (for IP K/V).
// grid (L, H), block 128
// ---------------------------------------------------------------------------
__global__ __launch_bounds__(128) void ip_norm_reorder(
    const float* __restrict__ src, const float* __restrict__ w,
    float* __restrict__ dst, int do_norm) {
  __shared__ float red[128];
  const int t = blockIdx.x, h = blockIdx.y, d = threadIdx.x;
  float v = src[(size_t)t * HID + h * DH + d];
  if (do_norm) {
    float ss = blk_sum128(v * v, red);
    v = v * rsqrtf(ss * (1.0f / DH) + 1e-6f) * w[d];
  }
  dst[((size_t)h * IPL + t) * DH + d] = v;
}

// ---------------------------------------------------------------------------
// IP attention: queries = rms(heads(Q)) with norm_ip_q_w; 128 keys.
// One block per (token, head); output pre-multiplied by bbox mask.
// grid (1024, 24), block 128.  Reads RAW Q (before in-place transform).
// ---------------------------------------------------------------------------
__global__ __launch_bounds__(128) void ip_attn(
    const float* __restrict__ Q, const float* __restrict__ KN,
    const float* __restrict__ VN, const float* __restrict__ qw,
    float* __restrict__ OUT) {
  const int t = blockIdx.x, h = blockIdx.y, d = threadIdx.x;
  const size_t qidx = (size_t)t * HID + h * DH + d;
  const size_t oidx = qidx;
  const int y = t >> 5, x = t & 31;
  if (!(y >= 8 && y < 24 && x >= 8 && x < 24)) { OUT[oidx] = 0.f; return; }
  __shared__ float qs[128], ps[128], red[128];
  float qv = Q[qidx];
  float ss = blk_sum128(qv * qv, red);
  qs[d] = qv * rsqrtf(ss * (1.0f / DH) + 1e-6f) * qw[d];
  __syncthreads();
  const float* krow = KN + ((size_t)h * IPL + d) * DH;  // thread d = key d
  float s = 0.f;
#pragma unroll 4
  for (int i = 0; i < 128; ++i) s += qs[i] * krow[i];
  s *= ATTN_SCALE;
  float mx = blk_max128(s, red);
  float p = __expf(s - mx);
  ps[d] = p;
  float lsum = blk_sum128(p, red);
  const float* vcol = VN + (size_t)h * IPL * DH + d;
  float o = 0.f;
#pragma unroll 4
  for (int j = 0; j < 128; ++j) o += ps[j] * vcol[(size_t)j * DH];
  OUT[oidx] = o / lsum;
}

// ---------------------------------------------------------------------------
// In-place per-head RMS + RoPE on the fused sequence (enc rows then img rows).
// grid (1536, 24), block 128. Row s<TXT lives in Xenc, else Ximg.
// ---------------------------------------------------------------------------
__global__ __launch_bounds__(128) void rms_rope_inplace(
    float* __restrict__ Xenc, float* __restrict__ Ximg,
    const float* __restrict__ w_enc, const float* __restrict__ w_img,
    const float* __restrict__ cosb, const float* __restrict__ sinb) {
  __shared__ float red[128];
  __shared__ float vs[128];
  const int s = blockIdx.x, h = blockIdx.y, d = threadIdx.x;
  float* p = ((s < TXT) ? Xenc + (size_t)s * HID : Ximg + (size_t)(s - TXT) * HID) + h * DH + d;
  float v = *p;
  float ss = blk_sum128(v * v, red);
  const float* w = (s < TXT) ? w_enc : w_img;
  v = v * rsqrtf(ss * (1.0f / DH) + 1e-6f) * w[d];
  vs[d] = v; __syncthreads();
  float other = (d & 1) ? vs[d - 1] : -vs[d + 1];
  *p = v * cosb[s * DH + d] + other * sinb[s * DH + d];
}

// ---------------------------------------------------------------------------
// Main attention, flash-style. 16 queries/block, 64-key tiles, online softmax.
// Sources are in (S, HID) layout split at TXT (enc buffers / img buffers);
// per-head column offset h*DH. TXT=512 is a multiple of 64 and 16, so a tile
// never straddles the split. Writes AOUT merged (S, H*DH); for image rows it
// ADDS the pre-masked IP output already sitting in AOUT's img region (each
// thread reads exactly the 4 floats it then overwrites). grid (96,24), blk 128.
// ---------------------------------------------------------------------------
__global__ __launch_bounds__(128) void flash_attn(
    const float* __restrict__ Qenc, const float* __restrict__ Qimg,
    const float* __restrict__ Kenc, const float* __restrict__ Kimg,
    const float* __restrict__ Venc, const float* __restrict__ Vimg,
    float* __restrict__ AOUT) {
  __shared__ float Qt[16][132];
  __shared__ float Kt[64][132];
  __shared__ float P[16][68];
  __shared__ float mL[16], lL[16], aL[16];
  const int h = blockIdx.y;
  const int s0 = blockIdx.x * 16;
  const int tid = threadIdx.x;
  const int kg = tid & 15;   // QK: 4 keys kg*4..+3
  const int qg = tid >> 4;   // QK: 2 queries qg*2..+1
  const int d4 = tid & 31;   // PV: 4 dims d4*4..+3
  const int qh = tid >> 5;   // PV: 4 queries qh*4..+3

  const float* qsrc = (s0 < TXT) ? (Qenc + (size_t)s0 * HID)
                                 : (Qimg + (size_t)(s0 - TXT) * HID);
  for (int e = tid; e < 16 * 128; e += 128)
    Qt[e >> 7][e & 127] = qsrc[(size_t)(e >> 7) * HID + h * DH + (e & 127)];
  if (tid < 16) { mL[tid] = -1e30f; lL[tid] = 0.f; }
  float O[4][4] = {};

  for (int kt = 0; kt < SFULL / 64; ++kt) {
    __syncthreads();  // protect Kt/P from previous iteration's readers
    const int ks = kt * 64;
    const float* ksrc = (ks < TXT) ? (Kenc + (size_t)ks * HID)
                                   : (Kimg + (size_t)(ks - TXT) * HID);
    for (int e = tid; e < 64 * 128; e += 128)
      Kt[e >> 7][e & 127] = ksrc[(size_t)(e >> 7) * HID + h * DH + (e & 127)];
    __syncthreads();
    // ---- QK^T: scores for 4 keys x 2 queries per thread
    {
      float s[4][2] = {};
#pragma unroll 4
      for (int dd = 0; dd < 128; dd += 4) {
        float4 q0 = *(const float4*)&Qt[qg * 2 + 0][dd];
        float4 q1 = *(const float4*)&Qt[qg * 2 + 1][dd];
#pragma unroll
        for (int i = 0; i < 4; ++i) {
          float4 kv = *(const float4*)&Kt[kg * 4 + i][dd];
          s[i][0] += kv.x * q0.x + kv.y * q0.y + kv.z * q0.z + kv.w * q0.w;
          s[i][1] += kv.x * q1.x + kv.y * q1.y + kv.z * q1.z + kv.w * q1.w;
        }
      }
#pragma unroll
      for (int i = 0; i < 4; ++i) {
        P[qg * 2 + 0][kg * 4 + i] = s[i][0] * ATTN_SCALE;
        P[qg * 2 + 1][kg * 4 + i] = s[i][1] * ATTN_SCALE;
      }
    }
    __syncthreads();
    // ---- online softmax bookkeeping (serial per query, 16 lanes busy)
    if (tid < 16) {
      const int q = tid;
      float mt = mL[q];
#pragma unroll 8
      for (int k = 0; k < 64; ++k) mt = fmaxf(mt, P[q][k]);
      float a = __expf(mL[q] - mt);
      float lsum = 0.f;
#pragma unroll 8
      for (int k = 0; k < 64; ++k) { float p = __expf(P[q][k] - mt); P[q][k] = p; lsum += p; }
      lL[q] = lL[q] * a + lsum;
      mL[q] = mt; aL[q] = a;
    }
    __syncthreads();
    // ---- P@V: 4 queries x 4 dims per thread, V streamed from L2
    {
#pragma unroll
      for (int qq = 0; qq < 4; ++qq) {
        float a = aL[qh * 4 + qq];
        O[qq][0] *= a; O[qq][1] *= a; O[qq][2] *= a; O[qq][3] *= a;
      }
      const float* vsrc = (ks < TXT) ? (Venc + (size_t)ks * HID)
                                     : (Vimg + (size_t)(ks - TXT) * HID);
      const float* vbase = vsrc + h * DH + d4 * 4;
      for (int k4 = 0; k4 < 64; k4 += 4) {
        float4 v0 = *(const float4*)(vbase + (size_t)(k4 + 0) * HID);
        float4 v1 = *(const float4*)(vbase + (size_t)(k4 + 1) * HID);
        float4 v2 = *(const float4*)(vbase + (size_t)(k4 + 2) * HID);
        float4 v3 = *(const float4*)(vbase + (size_t)(k4 + 3) * HID);
#pragma unroll
        for (int qq = 0; qq < 4; ++qq) {
          float4 p = *(const float4*)&P[qh * 4 + qq][k4];
          O[qq][0] += p.x * v0.x + p.y * v1.x + p.z * v2.x + p.w * v3.x;
          O[qq][1] += p.x * v0.y + p.y * v1.y + p.z * v2.y + p.w * v3.y;
          O[qq][2] += p.x * v0.z + p.y * v1.z + p.z * v2.z + p.w * v3.z;
          O[qq][3] += p.x * v0.w + p.y * v1.w + p.z * v2.w + p.w * v3.w;
        }
      }
    }
  }
  __syncthreads();
#pragma unroll
  for (int qq = 0; qq < 4; ++qq) {
    const int q = qh * 4 + qq;
    const int s = s0 + q;
    float inv = 1.0f / lL[q];
    float4 o = make_float4(O[qq][0] * inv, O[qq][1] * inv, O[qq][2] * inv, O[qq][3] * inv);
    float* dst = AOUT + (size_t)s * HID + h * DH + d4 * 4;
    if (s >= TXT) {  // add pre-masked IP output already stored here
      o.x += dst[0]; o.y += dst[1]; o.z += dst[2]; o.w += dst[3];
    }
    *(float4*)dst = o;
  }
}

// ---------------------------------------------------------------------------
extern "C" void kernel_launch(void* const* d_in, const int* in_sizes, int n_in,
                              void* d_out, int out_size, void* d_ws, size_t ws_size,
                              hipStream_t stream) {
  const float* x    = (const float*)d_in[0];
  const float* enc  = (const float*)d_in[1];
  const float* ip   = (const float*)d_in[2];
  const float* cosb = (const float*)d_in[3];
  const float* sinb = (const float*)d_in[4];
  const float* Wq   = (const float*)d_in[5];
  const float* bq   = (const float*)d_in[6];
  const float* Wk   = (const float*)d_in[7];
  const float* bk   = (const float*)d_in[8];
  const float* Wv   = (const float*)d_in[9];
  const float* bv   = (const float*)d_in[10];
  const float* nqw  = (const float*)d_in[11];
  const float* nkw  = (const float*)d_in[12];
  const float* Wqa  = (const float*)d_in[13];
  const float* bqa  = (const float*)d_in[14];
  const float* Wka  = (const float*)d_in[15];
  const float* bka  = (const float*)d_in[16];
  const float* Wva  = (const float*)d_in[17];
  const float* bva  = (const float*)d_in[18];
  const float* naqw = (const float*)d_in[19];
  const float* nakw = (const float*)d_in[20];
  const float* Wo   = (const float*)d_in[21];
  const float* bo   = (const float*)d_in[22];
  const float* Wao  = (const float*)d_in[23];
  const float* bao  = (const float*)d_in[24];
  const float* Wkip = (const float*)d_in[25];
  const float* bkip = (const float*)d_in[26];
  const float* Wvip = (const float*)d_in[27];
  const float* bvip = (const float*)d_in[28];
  const float* nipq = (const float*)d_in[29];
  const float* nipk = (const float*)d_in[30];

  float* out_img = (float*)d_out;                       // (1024, 3072)
  float* out_enc = (float*)d_out + (size_t)SIMG * HID;  // (512, 3072)

  float* ws = (float*)d_ws;
  // workspace layout (float offsets), total 19,660,800 floats = 78.6 MB
  float* Q    = ws + 0;          // 1024x3072  (raw -> in-place rms+rope)
  float* K    = ws + 3145728;    // 1024x3072
  float* V    = ws + 6291456;    // 1024x3072
  float* EQ   = ws + 9437184;    // 512x3072
  float* EK   = ws + 11010048;   // 512x3072
  float* EV   = ws + 12582912;   // 512x3072
  float* KIPN = ws + 14155776;   // (24,128,128)
  float* VIPN = ws + 14548992;   // (24,128,128)
  float* AOUT = ws + 14942208;   // 1536x3072
  // aliases into AOUT (dead/overwritten later):
  float* KIP  = AOUT;                      // 128x3072, enc-row region
  float* VIP  = AOUT + 393216;             // 128x3072, enc-row region
  float* IPO  = AOUT + (size_t)TXT * HID;  // 1024x3072, img-row region

  dim3 blk256(256), blk128(128);

  // 1. QKV projections (img tokens)
  gemm_bias<<<dim3(48, 16), blk256, 0, stream>>>(x, Wq, bq, Q, SIMG, HID, HID);
  gemm_bias<<<dim3(48, 16), blk256, 0, stream>>>(x, Wk, bk, K, SIMG, HID, HID);
  gemm_bias<<<dim3(48, 16), blk256, 0, stream>>>(x, Wv, bv, V, SIMG, HID, HID);
  // 2. IP K/V projections + normalize/reorder + IP attention (reads RAW Q,
  //    writes masked result into AOUT's img-row region)
  gemm_bias<<<dim3(48, 2), blk256, 0, stream>>>(ip, Wkip, bkip, KIP, IPL, HID, IPD);
  gemm_bias<<<dim3(48, 2), blk256, 0, stream>>>(ip, Wvip, bvip, VIP, IPL, HID, IPD);
  ip_norm_reorder<<<dim3(IPL, NH), blk128, 0, stream>>>(KIP, nipk, KIPN, 1);
  ip_norm_reorder<<<dim3(IPL, NH), blk128, 0, stream>>>(VIP, nullptr, VIPN, 0);
  ip_attn<<<dim3(SIMG, NH), blk128, 0, stream>>>(Q, KIPN, VIPN, nipq, IPO);
  // 3. encoder QKV projections
  gemm_bias<<<dim3(48, 8), blk256, 0, stream>>>(enc, Wqa, bqa, EQ, TXT, HID, HID);
  gemm_bias<<<dim3(48, 8), blk256, 0, stream>>>(enc, Wka, bka, EK, TXT, HID, HID);
  gemm_bias<<<dim3(48, 8), blk256, 0, stream>>>(enc, Wva, bva, EV, TXT, HID, HID);
  // 4. in-place RMS + RoPE on Q (enc+img) and K (enc+img); V needs none
  rms_rope_inplace<<<dim3(SFULL, NH), blk128, 0, stream>>>(EQ, Q, naqw, nqw, cosb, sinb);
  rms_rope_inplace<<<dim3(SFULL, NH), blk128, 0, stream>>>(EK, K, nakw, nkw, cosb, sinb);
  // 5. main attention; adds IP output in-place on img rows
  flash_attn<<<dim3(SFULL / 16, NH), blk128, 0, stream>>>(EQ, Q, EK, K, EV, V, AOUT);
  // 6. output projections straight to fp32 d_out
  gemm_bias<<<dim3(48, 16), blk256, 0, stream>>>(AOUT + (size_t)TXT * HID, Wo, bo, out_img, SIMG, HID, HID);
  gemm_bias<<<dim3(48, 8), blk256, 0, stream>>>(AOUT, Wao, bao, out_enc, TXT, HID, HID);
}